// Round 1
// baseline (1714.482 us; speedup 1.0000x reference)
//
#include <hip/hip_runtime.h>
#include <math.h>

#define B_ 8192
#define F_ 16
#define V_ 50000
#define D_ 32
#define NE_ 3
#define NL_ 3
#define EOD_ 512
#define M1_ 512
#define M2_ 256
#define M3_ 128

// ---------------- embedding gather ----------------
// es[e][b][f*32+d] = tables[e][x[b][f] + f*V][d]; one float4 per thread.
__global__ __launch_bounds__(256) void gather_k(const int* __restrict__ x,
    const float* __restrict__ tables, float* __restrict__ es)
{
    int gid = blockIdx.x * 256 + threadIdx.x;     // NE*B*F*8 exactly
    int d4 = gid & 7;
    int f  = (gid >> 3) & 15;
    int b  = (gid >> 7) & (B_ - 1);
    int e  = gid / (8 * F_ * B_);
    int idx = x[b * F_ + f] + f * V_;
    const float4* src = (const float4*)(tables + ((size_t)e * F_ * V_ + idx) * D_);
    float4* dst = (float4*)(es + ((size_t)e * B_ + b) * EOD_ + f * D_);
    dst[d4] = src[d4];
}

// ---------------- fused fp32 GEMM ----------------
// out(M,N) = epilogue(A(M,K) @ W(K,N) + bias)
// mode 0 (cross): out = x0 * (acc+bias) + xl      (requires N==K==512 layouts)
// mode 1 (mlp1):  out = (accum? out:0) + relu(acc+bias)/3
// mode 2 (relu):  out = relu(acc+bias)
__global__ __launch_bounds__(256) void gemm_k(
    const float* __restrict__ A, const float* __restrict__ W,
    const float* __restrict__ bias, const float* __restrict__ x0,
    const float* __restrict__ xl, float* __restrict__ out,
    int M, int N, int K, int mode, int accum)
{
    __shared__ float As[16][64];   // [k][m]
    __shared__ float Bs[16][64];   // [k][n]
    int t = threadIdx.x;
    int rowbase = blockIdx.y * 64, colbase = blockIdx.x * 64;
    int ty = t >> 4, tx = t & 15;
    int rb = ty * 4, cb = tx * 4;
    int arow = t >> 2, ak = (t & 3) * 4;
    int brow = t >> 4, bcol = (t & 15) * 4;

    float acc[4][4] = {};
    float4 av = *(const float4*)(A + (size_t)(rowbase + arow) * K + ak);
    float4 bv = *(const float4*)(W + (size_t)brow * N + colbase + bcol);

    for (int k0 = 0; k0 < K; k0 += 16) {
        __syncthreads();
        As[ak + 0][arow] = av.x; As[ak + 1][arow] = av.y;
        As[ak + 2][arow] = av.z; As[ak + 3][arow] = av.w;
        *(float4*)&Bs[brow][bcol] = bv;
        __syncthreads();
        if (k0 + 16 < K) {
            av = *(const float4*)(A + (size_t)(rowbase + arow) * K + (k0 + 16) + ak);
            bv = *(const float4*)(W + (size_t)(k0 + 16 + brow) * N + colbase + bcol);
        }
        #pragma unroll
        for (int kk = 0; kk < 16; kk++) {
            float4 a4 = *(const float4*)&As[kk][rb];
            float4 b4 = *(const float4*)&Bs[kk][cb];
            acc[0][0] += a4.x * b4.x; acc[0][1] += a4.x * b4.y; acc[0][2] += a4.x * b4.z; acc[0][3] += a4.x * b4.w;
            acc[1][0] += a4.y * b4.x; acc[1][1] += a4.y * b4.y; acc[1][2] += a4.y * b4.z; acc[1][3] += a4.y * b4.w;
            acc[2][0] += a4.z * b4.x; acc[2][1] += a4.z * b4.y; acc[2][2] += a4.z * b4.z; acc[2][3] += a4.z * b4.w;
            acc[3][0] += a4.w * b4.x; acc[3][1] += a4.w * b4.y; acc[3][2] += a4.w * b4.z; acc[3][3] += a4.w * b4.w;
        }
    }

    float4 bias4 = *(const float4*)(bias + colbase + cb);
    #pragma unroll
    for (int i = 0; i < 4; i++) {
        int row = rowbase + rb + i;
        size_t off = (size_t)row * N + colbase + cb;
        float4 v;
        v.x = acc[i][0] + bias4.x; v.y = acc[i][1] + bias4.y;
        v.z = acc[i][2] + bias4.z; v.w = acc[i][3] + bias4.w;
        if (mode == 0) {
            float4 xv = *(const float4*)(x0 + off);
            float4 lv = *(const float4*)(xl + off);
            v.x = xv.x * v.x + lv.x; v.y = xv.y * v.y + lv.y;
            v.z = xv.z * v.z + lv.z; v.w = xv.w * v.w + lv.w;
        } else if (mode == 1) {
            const float inv3 = 1.0f / 3.0f;
            v.x = fmaxf(v.x, 0.f) * inv3; v.y = fmaxf(v.y, 0.f) * inv3;
            v.z = fmaxf(v.z, 0.f) * inv3; v.w = fmaxf(v.w, 0.f) * inv3;
            if (accum) {
                float4 o = *(const float4*)(out + off);
                v.x += o.x; v.y += o.y; v.z += o.z; v.w += o.w;
            }
        } else {
            v.x = fmaxf(v.x, 0.f); v.y = fmaxf(v.y, 0.f);
            v.z = fmaxf(v.z, 0.f); v.w = fmaxf(v.w, 0.f);
        }
        *(float4*)(out + off) = v;
    }
}

// ---------------- final 128->1 dot + sigmoid ----------------
__global__ __launch_bounds__(256) void final_k(const float* __restrict__ h2,
    const float* __restrict__ W3, const float* __restrict__ b3,
    float* __restrict__ out)
{
    int gt = blockIdx.x * 256 + threadIdx.x;
    int s = gt >> 6, lane = gt & 63;
    float p = h2[(size_t)s * 128 + lane] * W3[lane]
            + h2[(size_t)s * 128 + 64 + lane] * W3[64 + lane];
    #pragma unroll
    for (int off = 32; off > 0; off >>= 1) p += __shfl_down(p, off);
    if (lane == 0) out[s] = 1.0f / (1.0f + expf(-(p + b3[0])));
}

// ---------------- pair Gram accumulation ----------------
// m[pair][k][d][e] = sum_b es[i][b][k*32+d] * es[j][b][k*32+e]
__global__ __launch_bounds__(256) void pairsum_k(const float* __restrict__ es,
                                                 float* __restrict__ m)
{
    const int pi[3] = {1, 2, 2};
    const int pj[3] = {0, 0, 1};
    int pk = blockIdx.x;             // 0..47
    int pair = pk >> 4, k = pk & 15;
    const float* Ei = es + (size_t)pi[pair] * B_ * EOD_ + k * D_;
    const float* Ej = es + (size_t)pj[pair] * B_ * EOD_ + k * D_;
    int b0 = blockIdx.y * (B_ / 16);

    __shared__ float sa[8][32], sb[8][32];
    int t = threadIdx.x;
    int d = t >> 3, e4 = (t & 7) * 4;
    int lr = t >> 5, lc = t & 31;
    float a0 = 0, a1 = 0, a2 = 0, a3 = 0;

    for (int bb = b0; bb < b0 + B_ / 16; bb += 8) {
        __syncthreads();
        sa[lr][lc] = Ei[(size_t)(bb + lr) * EOD_ + lc];
        sb[lr][lc] = Ej[(size_t)(bb + lr) * EOD_ + lc];
        __syncthreads();
        #pragma unroll
        for (int s2 = 0; s2 < 8; s2++) {
            float avv = sa[s2][d];
            float4 bvv = *(const float4*)&sb[s2][e4];
            a0 += avv * bvv.x; a1 += avv * bvv.y;
            a2 += avv * bvv.z; a3 += avv * bvv.w;
        }
    }
    float* dst = m + (size_t)pk * 1024 + d * 32 + e4;
    atomicAdd(dst + 0, a0); atomicAdd(dst + 1, a1);
    atomicAdd(dst + 2, a2); atomicAdd(dst + 3, a3);
}

// ---------------- batched 32x32 singular values via Jacobi on M^T M ----------------
__global__ __launch_bounds__(256) void svd_k(const float* __restrict__ mg,
                                             float* __restrict__ sv)
{
    __shared__ float Mm[32][33];
    __shared__ float G[32][33];
    __shared__ float rc[16], rs[16];
    __shared__ float ev[32];
    int t = threadIdx.x;
    int mat = blockIdx.x;

    for (int u = t; u < 1024; u += 256) Mm[u >> 5][u & 31] = mg[(size_t)mat * 1024 + u];
    __syncthreads();
    for (int u = t; u < 1024; u += 256) {
        int p = u >> 5, q = u & 31;
        float s = 0;
        #pragma unroll
        for (int dd = 0; dd < 32; dd++) s += Mm[dd][p] * Mm[dd][q];
        G[p][q] = s;
    }
    __syncthreads();

    for (int sweep = 0; sweep < 12; sweep++) {
        for (int r = 0; r < 31; r++) {
            if (t < 16) {
                int p, q;
                if (t == 0) { p = 31; q = r; }
                else { p = (r + t) % 31; q = (r + 31 - t) % 31; }
                float app = G[p][p], aqq = G[q][q], apq = G[p][q];
                float c = 1.f, s = 0.f;
                if (fabsf(apq) > 1e-12f) {
                    float tau = (aqq - app) / (2.f * apq);
                    float tt = (tau >= 0.f) ? 1.f / (tau + sqrtf(1.f + tau * tau))
                                            : 1.f / (tau - sqrtf(1.f + tau * tau));
                    c = rsqrtf(1.f + tt * tt); s = tt * c;
                }
                rc[t] = c; rs[t] = s;
            }
            __syncthreads();
            for (int u = t; u < 512; u += 256) {   // row update (J^T G)
                int pi_ = u >> 5, col = u & 31;
                int p, q;
                if (pi_ == 0) { p = 31; q = r; }
                else { p = (r + pi_) % 31; q = (r + 31 - pi_) % 31; }
                float c = rc[pi_], s = rs[pi_];
                float gp = G[p][col], gq = G[q][col];
                G[p][col] = c * gp - s * gq;
                G[q][col] = s * gp + c * gq;
            }
            __syncthreads();
            for (int u = t; u < 512; u += 256) {   // col update (G J)
                int pi_ = u >> 5, rw = u & 31;
                int p, q;
                if (pi_ == 0) { p = 31; q = r; }
                else { p = (r + pi_) % 31; q = (r + 31 - pi_) % 31; }
                float c = rc[pi_], s = rs[pi_];
                float gp = G[rw][p], gq = G[rw][q];
                G[rw][p] = c * gp - s * gq;
                G[rw][q] = s * gp + c * gq;
            }
            __syncthreads();
        }
    }

    if (t < 32) ev[t] = sqrtf(fmaxf(G[t][t], 0.f));
    __syncthreads();
    if (t < 32) {
        float v = ev[t]; int rank = 0;
        for (int o2 = 0; o2 < 32; o2++) {
            float w = ev[o2];
            if (w > v || (w == v && o2 < t)) rank++;
        }
        sv[(size_t)mat * 32 + rank] = v;   // descending order
    }
}

// ---------------- reg loss reduction ----------------
__global__ __launch_bounds__(128) void reg_k(const float* __restrict__ sv,
                                             float* __restrict__ out)
{
    __shared__ float red[128];
    int t = threadIdx.x;
    float val = 0.f;
    if (t < 96) {
        int p = t >> 5, d = t & 31;
        float s = 0;
        #pragma unroll
        for (int k = 0; k < 16; k++) s += sv[(size_t)(p * 16 + k) * 32 + d];
        s *= (1.f / 16.f);
        val = s * s;
    }
    red[t] = val; __syncthreads();
    for (int off = 64; off > 0; off >>= 1) {
        if (t < off) red[t] += red[t + off];
        __syncthreads();
    }
    if (t == 0) out[B_] = 0.01f * red[0] / 96.f;
}

extern "C" void kernel_launch(void* const* d_in, const int* in_sizes, int n_in,
                              void* d_out, int out_size, void* d_ws, size_t ws_size,
                              hipStream_t stream)
{
    const int*   x      = (const int*)d_in[0];
    const float* emb    = (const float*)d_in[1];
    const float* crossW = (const float*)d_in[2];
    const float* crossb = (const float*)d_in[3];
    const float* mlp1W  = (const float*)d_in[4];
    const float* mlp1b  = (const float*)d_in[5];
    const float* W1     = (const float*)d_in[6];
    const float* b1     = (const float*)d_in[7];
    const float* W2     = (const float*)d_in[8];
    const float* b2     = (const float*)d_in[9];
    const float* W3     = (const float*)d_in[10];
    const float* b3     = (const float*)d_in[11];
    float* out = (float*)d_out;
    float* ws  = (float*)d_ws;

    size_t o = 0;
    float* es   = ws + o; o += (size_t)NE_ * B_ * EOD_;   // 12.58M
    float* buf0 = ws + o; o += (size_t)B_ * EOD_;         // 4.19M
    float* buf1 = ws + o; o += (size_t)B_ * EOD_;         // 4.19M
    float* hsum = ws + o; o += (size_t)B_ * M1_;          // 4.19M
    float* h1   = ws + o; o += (size_t)B_ * M2_;          // 2.10M
    float* h2   = ws + o; o += (size_t)B_ * M3_;          // 1.05M
    float* mbuf = ws + o; o += 48 * 1024;
    float* sv   = ws + o; o += 48 * 32;

    hipMemsetAsync(mbuf, 0, 48 * 1024 * sizeof(float), stream);
    gather_k<<<(NE_ * B_ * F_ * 8) / 256, 256, 0, stream>>>(x, emb, es);

    // regularization path
    pairsum_k<<<dim3(48, 16), 256, 0, stream>>>(es, mbuf);
    svd_k<<<48, 256, 0, stream>>>(mbuf, sv);
    reg_k<<<1, 128, 0, stream>>>(sv, out);

    // main path
    for (int e = 0; e < NE_; e++) {
        const float* x0  = es + (size_t)e * B_ * EOD_;
        const float* cw  = crossW + (size_t)e * NL_ * EOD_ * EOD_;
        const float* cbp = crossb + (size_t)e * NL_ * EOD_;
        gemm_k<<<dim3(8, 128), 256, 0, stream>>>(x0,   cw,                      cbp,            x0, x0,   buf0, B_, EOD_, EOD_, 0, 0);
        gemm_k<<<dim3(8, 128), 256, 0, stream>>>(buf0, cw + (size_t)EOD_ * EOD_,     cbp + EOD_,     x0, buf0, buf1, B_, EOD_, EOD_, 0, 0);
        gemm_k<<<dim3(8, 128), 256, 0, stream>>>(buf1, cw + (size_t)2 * EOD_ * EOD_, cbp + 2 * EOD_, x0, buf1, buf0, B_, EOD_, EOD_, 0, 0);
        gemm_k<<<dim3(8, 128), 256, 0, stream>>>(buf0, mlp1W + (size_t)e * EOD_ * M1_, mlp1b + e * M1_,
                                                 nullptr, nullptr, hsum, B_, M1_, EOD_, 1, e > 0 ? 1 : 0);
    }
    gemm_k<<<dim3(4, 128), 256, 0, stream>>>(hsum, W1, b1, nullptr, nullptr, h1, B_, M2_, M1_, 2, 0);
    gemm_k<<<dim3(2, 128), 256, 0, stream>>>(h1,   W2, b2, nullptr, nullptr, h2, B_, M3_, M2_, 2, 0);
    final_k<<<(B_ * 64) / 256, 256, 0, stream>>>(h2, W3, b3, out);
}

// Round 2
// 1234.484 us; speedup vs baseline: 1.3888x; 1.3888x over previous
//
#include <hip/hip_runtime.h>
#include <math.h>

#define B_ 8192
#define F_ 16
#define V_ 50000
#define D_ 32
#define NE_ 3
#define EOD_ 512
#define M1_ 512
#define M2_ 256
#define M3_ 128

typedef __attribute__((ext_vector_type(8))) short short8;
typedef __attribute__((ext_vector_type(4))) float floatx4;

__device__ __forceinline__ unsigned short f2bf(float f) {
    union { float f; unsigned u; } v; v.f = f;
    unsigned r = v.u + 0x7FFF + ((v.u >> 16) & 1);
    return (unsigned short)(r >> 16);
}
__device__ __forceinline__ float bf2f(unsigned short h) {
    union { unsigned u; float f; } v; v.u = (unsigned)h << 16;
    return v.f;
}
// async global->LDS, 16B per lane; LDS dest must be wave-uniform base + lane*16
__device__ __forceinline__ void gld16(const void* g, void* l) {
    __builtin_amdgcn_global_load_lds(
        (const __attribute__((address_space(1))) unsigned int*)g,
        (__attribute__((address_space(3))) unsigned int*)l, 16, 0, 0);
}

// ---------------- embedding gather (fp32 tables -> bf16 es) ----------------
__global__ __launch_bounds__(256) void gather_k(const int* __restrict__ x,
    const float* __restrict__ tables, unsigned short* __restrict__ esb)
{
    int gid = blockIdx.x * 256 + threadIdx.x;   // NE*B*F*4 threads, 8 elems each
    int d8 = gid & 3;
    int f  = (gid >> 2) & 15;
    int b  = (gid >> 6) & (B_ - 1);
    int e  = gid >> 19;                          // B_*F_*4 = 2^19
    int idx = x[b * F_ + f] + f * V_;
    const float4* src = (const float4*)(tables + ((size_t)e * F_ * V_ + idx) * D_) + d8 * 2;
    float4 v0 = src[0], v1 = src[1];
    unsigned short o[8];
    o[0] = f2bf(v0.x); o[1] = f2bf(v0.y); o[2] = f2bf(v0.z); o[3] = f2bf(v0.w);
    o[4] = f2bf(v1.x); o[5] = f2bf(v1.y); o[6] = f2bf(v1.z); o[7] = f2bf(v1.w);
    unsigned short* dst = esb + ((size_t)e * B_ + b) * EOD_ + f * D_ + d8 * 8;
    *(uint4*)dst = *(uint4*)o;
}

// ---------------- weight transpose+convert: fp32 W[K][N] -> bf16 Wt[N][K] ----------------
__global__ __launch_bounds__(256) void wtrans_k(const float* __restrict__ W,
    unsigned short* __restrict__ Wt, int K, int N)
{
    __shared__ float tile[32][33];
    int bn = blockIdx.x * 32, bk = blockIdx.y * 32;
    int mat = blockIdx.z;
    const float* Wm = W + (size_t)mat * K * N;
    unsigned short* Wtm = Wt + (size_t)mat * K * N;
    int tx = threadIdx.x & 31, ty = threadIdx.x >> 5;   // 32 x 8
    #pragma unroll
    for (int i = 0; i < 32; i += 8)
        tile[ty + i][tx] = Wm[(size_t)(bk + ty + i) * N + bn + tx];
    __syncthreads();
    #pragma unroll
    for (int i = 0; i < 32; i += 8)
        Wtm[(size_t)(bn + ty + i) * K + bk + tx] = f2bf(tile[tx][ty + i]);
}

// ---------------- bf16 MFMA GEMM, 128x128 tile, BK=32 ----------------
// out = epi(A[M][K] @ Wt[N][K]^T + bias)
// mode 0: v = x0*v + xl       (bf16 out)
// mode 1: v = relu(v)/3 (+outf if accum); writes outf fp32, outb optional
// mode 2: v = relu(v); outf/outb optional
__global__ __launch_bounds__(256) void gemm_mfma_k(
    const unsigned short* __restrict__ A,
    const unsigned short* __restrict__ Wt,
    const float* __restrict__ bias,
    const unsigned short* __restrict__ x0,
    const unsigned short* __restrict__ xl,
    float* __restrict__ outf,
    unsigned short* __restrict__ outb,
    int M, int N, int K, int mode, int accum)
{
    __shared__ unsigned short As[128 * 32];
    __shared__ unsigned short Bs[128 * 32];
    int t = threadIdx.x;
    int w = t >> 6, lane = t & 63;
    int quad = lane >> 4, lid = lane & 15;
    int wr = (w & 1) * 64, wc = (w >> 1) * 64;
    int rowbase = blockIdx.y * 128, colbase = blockIdx.x * 128;

    // staging: wave w fills chunks {2w, 2w+1} of each 8KB LDS tile.
    // chunk = 16 rows; lane covers row chunk*16 + lane/4, k-span (lane&3)*8..+8
    int chunk = w * 2;
    int sub = lane >> 2;
    int kk = (lane & 3) * 8;
    const unsigned short* pa0 = A  + (size_t)(rowbase + chunk * 16 + sub) * K + kk;
    const unsigned short* pa1 = pa0 + (size_t)16 * K;
    const unsigned short* pb0 = Wt + (size_t)(colbase + chunk * 16 + sub) * K + kk;
    const unsigned short* pb1 = pb0 + (size_t)16 * K;
    unsigned short* la0 = As + chunk * 512 + lane * 8;
    unsigned short* la1 = la0 + 512;
    unsigned short* lb0 = Bs + chunk * 512 + lane * 8;
    unsigned short* lb1 = lb0 + 512;

    floatx4 acc[4][4];
    #pragma unroll
    for (int i = 0; i < 4; i++)
        #pragma unroll
        for (int j = 0; j < 4; j++) acc[i][j] = {0.f, 0.f, 0.f, 0.f};

    for (int k0 = 0; k0 < K; k0 += 32) {
        if (k0) __syncthreads();
        gld16(pa0 + k0, la0);
        gld16(pa1 + k0, la1);
        gld16(pb0 + k0, lb0);
        gld16(pb1 + k0, lb1);
        __syncthreads();
        short8 af[4], bfr[4];
        #pragma unroll
        for (int i = 0; i < 4; i++) {
            af[i]  = *(const short8*)(As + (wr + i * 16 + lid) * 32 + quad * 8);
            bfr[i] = *(const short8*)(Bs + (wc + i * 16 + lid) * 32 + quad * 8);
        }
        #pragma unroll
        for (int i = 0; i < 4; i++)
            #pragma unroll
            for (int j = 0; j < 4; j++)
                acc[i][j] = __builtin_amdgcn_mfma_f32_16x16x32_bf16(af[i], bfr[j], acc[i][j], 0, 0, 0);
    }

    // C/D layout: col = lane&15, row = quad*4 + reg
    #pragma unroll
    for (int i = 0; i < 4; i++) {
        int row0 = rowbase + wr + i * 16 + quad * 4;
        #pragma unroll
        for (int j = 0; j < 4; j++) {
            int col = colbase + wc + j * 16 + lid;
            float bv = bias[col];
            #pragma unroll
            for (int r = 0; r < 4; r++) {
                size_t off = (size_t)(row0 + r) * N + col;
                float v = acc[i][j][r] + bv;
                if (mode == 0) {
                    v = bf2f(x0[off]) * v + bf2f(xl[off]);
                } else if (mode == 1) {
                    v = fmaxf(v, 0.f) * (1.f / 3.f);
                    if (accum) v += outf[off];
                    outf[off] = v;
                } else {
                    v = fmaxf(v, 0.f);
                    if (outf) outf[off] = v;
                }
                if (outb) outb[off] = f2bf(v);
            }
        }
    }
}

// ---------------- final 128->1 dot + sigmoid ----------------
__global__ __launch_bounds__(256) void final_k(const float* __restrict__ h2,
    const float* __restrict__ W3, const float* __restrict__ b3,
    float* __restrict__ out)
{
    int gt = blockIdx.x * 256 + threadIdx.x;
    int s = gt >> 6, lane = gt & 63;
    float p = h2[(size_t)s * 128 + lane] * W3[lane]
            + h2[(size_t)s * 128 + 64 + lane] * W3[64 + lane];
    #pragma unroll
    for (int off = 32; off > 0; off >>= 1) p += __shfl_down(p, off);
    if (lane == 0) out[s] = 1.0f / (1.0f + expf(-(p + b3[0])));
}

// ---------------- pair Gram accumulation (bf16 in, fp32 accum) ----------------
__global__ __launch_bounds__(256) void pairsum_k(const unsigned short* __restrict__ es,
                                                 float* __restrict__ m)
{
    const int pi[3] = {1, 2, 2};
    const int pj[3] = {0, 0, 1};
    int pk = blockIdx.x;             // 0..47
    int pair = pk >> 4, k = pk & 15;
    const unsigned short* Ei = es + (size_t)pi[pair] * B_ * EOD_ + k * D_;
    const unsigned short* Ej = es + (size_t)pj[pair] * B_ * EOD_ + k * D_;
    int b0 = blockIdx.y * (B_ / 16);

    __shared__ float sa[8][32], sb[8][32];
    int t = threadIdx.x;
    int d = t >> 3, e4 = (t & 7) * 4;
    int lr = t >> 5, lc = t & 31;
    float a0 = 0, a1 = 0, a2 = 0, a3 = 0;

    for (int bb = b0; bb < b0 + B_ / 16; bb += 8) {
        __syncthreads();
        sa[lr][lc] = bf2f(Ei[(size_t)(bb + lr) * EOD_ + lc]);
        sb[lr][lc] = bf2f(Ej[(size_t)(bb + lr) * EOD_ + lc]);
        __syncthreads();
        #pragma unroll
        for (int s2 = 0; s2 < 8; s2++) {
            float avv = sa[s2][d];
            float4 bvv = *(const float4*)&sb[s2][e4];
            a0 += avv * bvv.x; a1 += avv * bvv.y;
            a2 += avv * bvv.z; a3 += avv * bvv.w;
        }
    }
    float* dst = m + (size_t)pk * 1024 + d * 32 + e4;
    atomicAdd(dst + 0, a0); atomicAdd(dst + 1, a1);
    atomicAdd(dst + 2, a2); atomicAdd(dst + 3, a3);
}

// ---------------- 32x32 singular values, one wave per matrix, 6 sweeps ----------------
__global__ __launch_bounds__(64) void svd_k(const float* __restrict__ mg,
                                            float* __restrict__ sv)
{
    __shared__ float Mm[32][33];
    __shared__ float G[32][33];
    __shared__ float rc[16], rs[16];
    __shared__ float ev[32];
    int t = threadIdx.x;
    int mat = blockIdx.x;

    for (int u = t; u < 1024; u += 64) Mm[u >> 5][u & 31] = mg[(size_t)mat * 1024 + u];
    __syncthreads();
    for (int u = t; u < 1024; u += 64) {
        int p = u >> 5, q = u & 31;
        float s = 0;
        #pragma unroll
        for (int dd = 0; dd < 32; dd++) s += Mm[dd][p] * Mm[dd][q];
        G[p][q] = s;
    }
    __syncthreads();

    for (int sweep = 0; sweep < 6; sweep++) {
        for (int r = 0; r < 31; r++) {
            if (t < 16) {
                int p, q;
                if (t == 0) { p = 31; q = r; }
                else { p = (r + t) % 31; q = (r + 31 - t) % 31; }
                float app = G[p][p], aqq = G[q][q], apq = G[p][q];
                float c = 1.f, s = 0.f;
                if (fabsf(apq) > 1e-12f) {
                    float tau = (aqq - app) / (2.f * apq);
                    float tt = (tau >= 0.f) ? 1.f / (tau + sqrtf(1.f + tau * tau))
                                            : 1.f / (tau - sqrtf(1.f + tau * tau));
                    c = rsqrtf(1.f + tt * tt); s = tt * c;
                }
                rc[t] = c; rs[t] = s;
            }
            __syncthreads();
            for (int u = t; u < 512; u += 64) {   // row update (J^T G)
                int pi_ = u >> 5, col = u & 31;
                int p, q;
                if (pi_ == 0) { p = 31; q = r; }
                else { p = (r + pi_) % 31; q = (r + 31 - pi_) % 31; }
                float c = rc[pi_], s = rs[pi_];
                float gp = G[p][col], gq = G[q][col];
                G[p][col] = c * gp - s * gq;
                G[q][col] = s * gp + c * gq;
            }
            __syncthreads();
            for (int u = t; u < 512; u += 64) {   // col update (G J)
                int pi_ = u >> 5, rw = u & 31;
                int p, q;
                if (pi_ == 0) { p = 31; q = r; }
                else { p = (r + pi_) % 31; q = (r + 31 - pi_) % 31; }
                float c = rc[pi_], s = rs[pi_];
                float gp = G[rw][p], gq = G[rw][q];
                G[rw][p] = c * gp - s * gq;
                G[rw][q] = s * gp + c * gq;
            }
            __syncthreads();
        }
    }

    if (t < 32) ev[t] = sqrtf(fmaxf(G[t][t], 0.f));
    __syncthreads();
    if (t < 32) {
        float v = ev[t]; int rank = 0;
        for (int o2 = 0; o2 < 32; o2++) {
            float w = ev[o2];
            if (w > v || (w == v && o2 < t)) rank++;
        }
        sv[(size_t)mat * 32 + rank] = v;
    }
}

// ---------------- reg loss reduction ----------------
__global__ __launch_bounds__(128) void reg_k(const float* __restrict__ sv,
                                             float* __restrict__ out)
{
    __shared__ float red[128];
    int t = threadIdx.x;
    float val = 0.f;
    if (t < 96) {
        int p = t >> 5, d = t & 31;
        float s = 0;
        #pragma unroll
        for (int k = 0; k < 16; k++) s += sv[(size_t)(p * 16 + k) * 32 + d];
        s *= (1.f / 16.f);
        val = s * s;
    }
    red[t] = val; __syncthreads();
    for (int off = 64; off > 0; off >>= 1) {
        if (t < off) red[t] += red[t + off];
        __syncthreads();
    }
    if (t == 0) out[B_] = 0.01f * red[0] / 96.f;
}

extern "C" void kernel_launch(void* const* d_in, const int* in_sizes, int n_in,
                              void* d_out, int out_size, void* d_ws, size_t ws_size,
                              hipStream_t stream)
{
    const int*   x      = (const int*)d_in[0];
    const float* emb    = (const float*)d_in[1];
    const float* crossW = (const float*)d_in[2];
    const float* crossb = (const float*)d_in[3];
    const float* mlp1W  = (const float*)d_in[4];
    const float* mlp1b  = (const float*)d_in[5];
    const float* W1     = (const float*)d_in[6];
    const float* b1     = (const float*)d_in[7];
    const float* W2     = (const float*)d_in[8];
    const float* b2     = (const float*)d_in[9];
    const float* W3     = (const float*)d_in[10];
    const float* b3     = (const float*)d_in[11];
    float* out = (float*)d_out;

    unsigned char* wsb = (unsigned char*)d_ws;
    size_t o = 0;
    auto alloc = [&](size_t bytes) -> void* {
        void* p = wsb + o; o += (bytes + 255) & ~(size_t)255; return p;
    };
    unsigned short* esb  = (unsigned short*)alloc((size_t)NE_ * B_ * EOD_ * 2);
    unsigned short* b0b  = (unsigned short*)alloc((size_t)B_ * EOD_ * 2);
    unsigned short* b1b  = (unsigned short*)alloc((size_t)B_ * EOD_ * 2);
    float*          hsum = (float*)alloc((size_t)B_ * M1_ * 4);
    unsigned short* hsb  = (unsigned short*)alloc((size_t)B_ * M1_ * 2);
    unsigned short* h1b  = (unsigned short*)alloc((size_t)B_ * M2_ * 2);
    float*          h2   = (float*)alloc((size_t)B_ * M3_ * 4);
    unsigned short* WtC  = (unsigned short*)alloc((size_t)9 * 512 * 512 * 2);
    unsigned short* WtM  = (unsigned short*)alloc((size_t)3 * 512 * 512 * 2);
    unsigned short* Wt1  = (unsigned short*)alloc((size_t)512 * 256 * 2);
    unsigned short* Wt2  = (unsigned short*)alloc((size_t)256 * 128 * 2);
    float*          mbuf = (float*)alloc(48 * 1024 * 4);
    float*          sv   = (float*)alloc(48 * 32 * 4);

    // weights -> bf16 transposed [N][K]
    wtrans_k<<<dim3(16, 16, 9), 256, 0, stream>>>(crossW, WtC, 512, 512);
    wtrans_k<<<dim3(16, 16, 3), 256, 0, stream>>>(mlp1W,  WtM, 512, 512);
    wtrans_k<<<dim3( 8, 16, 1), 256, 0, stream>>>(W1, Wt1, 512, 256);
    wtrans_k<<<dim3( 4,  8, 1), 256, 0, stream>>>(W2, Wt2, 256, 128);

    gather_k<<<(NE_ * B_ * F_ * 4) / 256, 256, 0, stream>>>(x, emb, esb);

    // regularization path
    hipMemsetAsync(mbuf, 0, 48 * 1024 * 4, stream);
    pairsum_k<<<dim3(48, 16), 256, 0, stream>>>(esb, mbuf);
    svd_k<<<48, 64, 0, stream>>>(mbuf, sv);
    reg_k<<<1, 128, 0, stream>>>(sv, out);

    // main path
    for (int e = 0; e < NE_; e++) {
        const unsigned short* x0 = esb + (size_t)e * B_ * EOD_;
        const unsigned short* cw = WtC + (size_t)e * 3 * 512 * 512;
        const float* cb = crossb + (size_t)e * 3 * EOD_;
        gemm_mfma_k<<<dim3(4, 64), 256, 0, stream>>>(x0,  cw,              cb,            x0, x0,  nullptr, b0b, B_, EOD_, EOD_, 0, 0);
        gemm_mfma_k<<<dim3(4, 64), 256, 0, stream>>>(b0b, cw + 512 * 512,  cb + EOD_,     x0, b0b, nullptr, b1b, B_, EOD_, EOD_, 0, 0);
        gemm_mfma_k<<<dim3(4, 64), 256, 0, stream>>>(b1b, cw + 2 * 512 * 512, cb + 2 * EOD_, x0, b1b, nullptr, b0b, B_, EOD_, EOD_, 0, 0);
        gemm_mfma_k<<<dim3(4, 64), 256, 0, stream>>>(b0b, WtM + (size_t)e * 512 * 512, mlp1b + e * M1_,
                                                     nullptr, nullptr, hsum, (e == 2) ? hsb : nullptr,
                                                     B_, M1_, EOD_, 1, e > 0 ? 1 : 0);
    }
    gemm_mfma_k<<<dim3(2, 64), 256, 0, stream>>>(hsb, Wt1, b1, nullptr, nullptr, nullptr, h1b, B_, M2_, M1_, 2, 0);
    gemm_mfma_k<<<dim3(1, 64), 256, 0, stream>>>(h1b, Wt2, b2, nullptr, nullptr, h2, nullptr, B_, M3_, M2_, 2, 0);
    final_k<<<(B_ * 64) / 256, 256, 0, stream>>>(h2, W3, b3, out);
}

// Round 3
// 817.010 us; speedup vs baseline: 2.0985x; 1.5110x over previous
//
#include <hip/hip_runtime.h>
#include <math.h>

#define B_ 8192
#define F_ 16
#define V_ 50000
#define D_ 32
#define NE_ 3
#define EOD_ 512
#define M1_ 512
#define M2_ 256
#define M3_ 128
#define BE_ ((size_t)B_ * EOD_)

typedef __attribute__((ext_vector_type(8))) short short8;
typedef __attribute__((ext_vector_type(4))) float floatx4;

__device__ __forceinline__ unsigned short f2bf(float f) {
    union { float f; unsigned u; } v; v.f = f;
    unsigned r = v.u + 0x7FFF + ((v.u >> 16) & 1);
    return (unsigned short)(r >> 16);
}
__device__ __forceinline__ float bf2f(unsigned short h) {
    union { unsigned u; float f; } v; v.u = (unsigned)h << 16;
    return v.f;
}
// async global->LDS, 16B per lane; LDS dest must be wave-uniform base + lane*16
__device__ __forceinline__ void gld16(const void* g, void* l) {
    __builtin_amdgcn_global_load_lds(
        (const __attribute__((address_space(1))) unsigned int*)g,
        (__attribute__((address_space(3))) unsigned int*)l, 16, 0, 0);
}

// ---------------- embedding gather (fp32 tables -> bf16 es) ----------------
__global__ __launch_bounds__(256) void gather_k(const int* __restrict__ x,
    const float* __restrict__ tables, unsigned short* __restrict__ esb)
{
    int gid = blockIdx.x * 256 + threadIdx.x;   // NE*B*F*4 threads, 8 elems each
    int d8 = gid & 3;
    int f  = (gid >> 2) & 15;
    int b  = (gid >> 6) & (B_ - 1);
    int e  = gid >> 19;
    int idx = x[b * F_ + f] + f * V_;
    const float4* src = (const float4*)(tables + ((size_t)e * F_ * V_ + idx) * D_) + d8 * 2;
    float4 v0 = src[0], v1 = src[1];
    unsigned short o[8];
    o[0] = f2bf(v0.x); o[1] = f2bf(v0.y); o[2] = f2bf(v0.z); o[3] = f2bf(v0.w);
    o[4] = f2bf(v1.x); o[5] = f2bf(v1.y); o[6] = f2bf(v1.z); o[7] = f2bf(v1.w);
    unsigned short* dst = esb + ((size_t)e * B_ + b) * EOD_ + f * D_ + d8 * 8;
    *(uint4*)dst = *(uint4*)o;
}

// ---------------- weight transpose+convert: fp32 W[K][N] -> bf16 Wt[N][K] ----------------
__global__ __launch_bounds__(256) void wtrans_k(const float* __restrict__ W,
    unsigned short* __restrict__ Wt, int K, int N)
{
    __shared__ float tile[32][33];
    int bn = blockIdx.x * 32, bk = blockIdx.y * 32;
    int mat = blockIdx.z;
    const float* Wm = W + (size_t)mat * K * N;
    unsigned short* Wtm = Wt + (size_t)mat * K * N;
    int tx = threadIdx.x & 31, ty = threadIdx.x >> 5;   // 32 x 8
    #pragma unroll
    for (int i = 0; i < 32; i += 8)
        tile[ty + i][tx] = Wm[(size_t)(bk + ty + i) * N + bn + tx];
    __syncthreads();
    #pragma unroll
    for (int i = 0; i < 32; i += 8)
        Wtm[(size_t)(bn + ty + i) * K + bk + tx] = f2bf(tile[tx][ty + i]);
}

// ---------------- bf16 MFMA GEMM, 128x128 tile, BK=32, z-batched ----------------
// out = epi(A[M][K] @ Wt[N][K]^T + bias); per-e strides via blockIdx.z
// mode 0: v = x0*v + xl ; mode 1: v = relu(v)/3 ; mode 2: v = relu(v)
__global__ __launch_bounds__(256) void gemm_mfma_k(
    const unsigned short* __restrict__ A,  long sA,
    const unsigned short* __restrict__ Wt, long sW,
    const float* __restrict__ bias,        long sB,
    const unsigned short* __restrict__ x0, long sX,
    const unsigned short* __restrict__ xl, long sXl,
    unsigned short* __restrict__ outb,     long sO,
    int M, int N, int K, int mode)
{
    int e = blockIdx.z;
    A    += (size_t)e * sA;
    Wt   += (size_t)e * sW;
    bias += (size_t)e * sB;
    outb += (size_t)e * sO;
    if (mode == 0) { x0 += (size_t)e * sX; xl += (size_t)e * sXl; }

    __shared__ unsigned short As[128 * 32];
    __shared__ unsigned short Bs[128 * 32];
    int t = threadIdx.x;
    int w = t >> 6, lane = t & 63;
    int quad = lane >> 4, lid = lane & 15;
    int wr = (w & 1) * 64, wc = (w >> 1) * 64;
    int rowbase = blockIdx.y * 128, colbase = blockIdx.x * 128;

    int chunk = w * 2;
    int sub = lane >> 2;
    int kk = (lane & 3) * 8;
    const unsigned short* pa0 = A  + (size_t)(rowbase + chunk * 16 + sub) * K + kk;
    const unsigned short* pa1 = pa0 + (size_t)16 * K;
    const unsigned short* pb0 = Wt + (size_t)(colbase + chunk * 16 + sub) * K + kk;
    const unsigned short* pb1 = pb0 + (size_t)16 * K;
    unsigned short* la0 = As + chunk * 512 + lane * 8;
    unsigned short* la1 = la0 + 512;
    unsigned short* lb0 = Bs + chunk * 512 + lane * 8;
    unsigned short* lb1 = lb0 + 512;

    floatx4 acc[4][4];
    #pragma unroll
    for (int i = 0; i < 4; i++)
        #pragma unroll
        for (int j = 0; j < 4; j++) acc[i][j] = {0.f, 0.f, 0.f, 0.f};

    for (int k0 = 0; k0 < K; k0 += 32) {
        if (k0) __syncthreads();
        gld16(pa0 + k0, la0);
        gld16(pa1 + k0, la1);
        gld16(pb0 + k0, lb0);
        gld16(pb1 + k0, lb1);
        __syncthreads();
        short8 af[4], bfr[4];
        #pragma unroll
        for (int i = 0; i < 4; i++) {
            af[i]  = *(const short8*)(As + (wr + i * 16 + lid) * 32 + quad * 8);
            bfr[i] = *(const short8*)(Bs + (wc + i * 16 + lid) * 32 + quad * 8);
        }
        #pragma unroll
        for (int i = 0; i < 4; i++)
            #pragma unroll
            for (int j = 0; j < 4; j++)
                acc[i][j] = __builtin_amdgcn_mfma_f32_16x16x32_bf16(af[i], bfr[j], acc[i][j], 0, 0, 0);
    }

    // C/D layout: col = lane&15, row = quad*4 + reg
    #pragma unroll
    for (int i = 0; i < 4; i++) {
        int row0 = rowbase + wr + i * 16 + quad * 4;
        #pragma unroll
        for (int j = 0; j < 4; j++) {
            int col = colbase + wc + j * 16 + lid;
            float bv = bias[col];
            #pragma unroll
            for (int rr = 0; rr < 4; rr++) {
                size_t off = (size_t)(row0 + rr) * N + col;
                float v = acc[i][j][rr] + bv;
                if (mode == 0)      v = bf2f(x0[off]) * v + bf2f(xl[off]);
                else if (mode == 1) v = fmaxf(v, 0.f) * (1.f / 3.f);
                else                v = fmaxf(v, 0.f);
                outb[off] = f2bf(v);
            }
        }
    }
}

// ---------------- sum of 3 per-e mlp1 outputs (bf16) ----------------
__global__ __launch_bounds__(256) void sum3_k(const unsigned short* __restrict__ h,
                                              unsigned short* __restrict__ o)
{
    size_t i = ((size_t)blockIdx.x * 256 + threadIdx.x) * 8;
    uint4 a = *(const uint4*)(h + i);
    uint4 b = *(const uint4*)(h + BE_ + i);
    uint4 c = *(const uint4*)(h + 2 * BE_ + i);
    const unsigned short* pa = (const unsigned short*)&a;
    const unsigned short* pb = (const unsigned short*)&b;
    const unsigned short* pc = (const unsigned short*)&c;
    unsigned short r[8];
    #pragma unroll
    for (int j = 0; j < 8; j++) r[j] = f2bf(bf2f(pa[j]) + bf2f(pb[j]) + bf2f(pc[j]));
    *(uint4*)(o + i) = *(uint4*)r;
}

// ---------------- final 128->1 dot + sigmoid (bf16 h2) ----------------
__global__ __launch_bounds__(256) void final_k(const unsigned short* __restrict__ h2,
    const float* __restrict__ W3, const float* __restrict__ b3,
    float* __restrict__ out)
{
    int gt = blockIdx.x * 256 + threadIdx.x;
    int s = gt >> 6, lane = gt & 63;
    float p = bf2f(h2[(size_t)s * 128 + lane]) * W3[lane]
            + bf2f(h2[(size_t)s * 128 + 64 + lane]) * W3[64 + lane];
    #pragma unroll
    for (int off = 32; off > 0; off >>= 1) p += __shfl_down(p, off);
    if (lane == 0) out[s] = 1.0f / (1.0f + expf(-(p + b3[0])));
}

// ---------------- pair Gram accumulation (bf16 in, fp32 accum) ----------------
__global__ __launch_bounds__(256) void pairsum_k(const unsigned short* __restrict__ es,
                                                 float* __restrict__ m)
{
    const int pi[3] = {1, 2, 2};
    const int pj[3] = {0, 0, 1};
    int pk = blockIdx.x;             // 0..47
    int pair = pk >> 4, k = pk & 15;
    const unsigned short* Ei = es + (size_t)pi[pair] * BE_ + k * D_;
    const unsigned short* Ej = es + (size_t)pj[pair] * BE_ + k * D_;
    int b0 = blockIdx.y * (B_ / 16);

    __shared__ float sa[8][32], sb[8][32];
    int t = threadIdx.x;
    int d = t >> 3, e4 = (t & 7) * 4;
    int lr = t >> 5, lc = t & 31;
    float a0 = 0, a1 = 0, a2 = 0, a3 = 0;

    for (int bb = b0; bb < b0 + B_ / 16; bb += 8) {
        __syncthreads();
        sa[lr][lc] = bf2f(Ei[(size_t)(bb + lr) * EOD_ + lc]);
        sb[lr][lc] = bf2f(Ej[(size_t)(bb + lr) * EOD_ + lc]);
        __syncthreads();
        #pragma unroll
        for (int s2 = 0; s2 < 8; s2++) {
            float avv = sa[s2][d];
            float4 bvv = *(const float4*)&sb[s2][e4];
            a0 += avv * bvv.x; a1 += avv * bvv.y;
            a2 += avv * bvv.z; a3 += avv * bvv.w;
        }
    }
    float* dst = m + (size_t)pk * 1024 + d * 32 + e4;
    atomicAdd(dst + 0, a0); atomicAdd(dst + 1, a1);
    atomicAdd(dst + 2, a2); atomicAdd(dst + 3, a3);
}

// ---------------- 32x32 singular values: 1 wave/matrix, 4 matrices/block ----------------
// No __syncthreads: each wave owns its matrix; intra-wave LDS ordering is
// guaranteed by program order (compiler-inserted lgkmcnt waits).
__global__ __launch_bounds__(256) void svd_k(const float* __restrict__ mg,
                                             float* __restrict__ sv)
{
    __shared__ float Mm[4][32][32];
    __shared__ float G[4][32][33];
    __shared__ float rc[4][16], rs[4][16];
    int t = threadIdx.x;
    int w = t >> 6, l = t & 63;
    int mat = blockIdx.x * 4 + w;
    float (*Gm)[33] = G[w];
    float (*Mw)[32] = Mm[w];

    const float* src = mg + (size_t)mat * 1024;
    for (int u = l; u < 1024; u += 64) Mw[u >> 5][u & 31] = src[u];
    for (int u = l; u < 1024; u += 64) {
        int p = u >> 5, q = u & 31;
        float s = 0;
        #pragma unroll
        for (int dd = 0; dd < 32; dd++) s += Mw[dd][p] * Mw[dd][q];
        Gm[p][q] = s;
    }

    int colr = l & 31, half = l >> 5;
    for (int sweep = 0; sweep < 6; sweep++) {
        for (int r = 0; r < 31; r++) {
            if (l < 16) {
                int p, q;
                if (l == 0) { p = 31; q = r; }
                else { p = (r + l) % 31; q = (r + 31 - l) % 31; }
                float app = Gm[p][p], aqq = Gm[q][q], apq = Gm[p][q];
                float c = 1.f, s = 0.f;
                if (fabsf(apq) > 1e-12f) {
                    float tau = (aqq - app) / (2.f * apq);
                    float tt = (tau >= 0.f) ? 1.f / (tau + sqrtf(1.f + tau * tau))
                                            : 1.f / (tau - sqrtf(1.f + tau * tau));
                    c = rsqrtf(1.f + tt * tt); s = tt * c;
                }
                rc[w][l] = c; rs[w][l] = s;
            }
            int ps[8], qs[8];
            float cc[8], ssv[8], gp[8], gq[8];
            // row update: J^T G  (batch 16 loads, then 16 stores)
            #pragma unroll
            for (int j = 0; j < 8; j++) {
                int pi_ = half + 2 * j;
                int p, q;
                if (pi_ == 0) { p = 31; q = r; }
                else { p = (r + pi_) % 31; q = (r + 31 - pi_) % 31; }
                ps[j] = p; qs[j] = q;
                cc[j] = rc[w][pi_]; ssv[j] = rs[w][pi_];
                gp[j] = Gm[p][colr]; gq[j] = Gm[q][colr];
            }
            #pragma unroll
            for (int j = 0; j < 8; j++) {
                Gm[ps[j]][colr] = cc[j] * gp[j] - ssv[j] * gq[j];
                Gm[qs[j]][colr] = ssv[j] * gp[j] + cc[j] * gq[j];
            }
            // col update: (J^T G) J
            #pragma unroll
            for (int j = 0; j < 8; j++) {
                gp[j] = Gm[colr][ps[j]];
                gq[j] = Gm[colr][qs[j]];
            }
            #pragma unroll
            for (int j = 0; j < 8; j++) {
                Gm[colr][ps[j]] = cc[j] * gp[j] - ssv[j] * gq[j];
                Gm[colr][qs[j]] = ssv[j] * gp[j] + cc[j] * gq[j];
            }
        }
    }

    if (l < 32) Mw[0][l] = sqrtf(fmaxf(Gm[l][l], 0.f));
    if (l < 32) {
        float v = Mw[0][l];
        int rank = 0;
        for (int o2 = 0; o2 < 32; o2++) {
            float u2 = Mw[0][o2];
            if (u2 > v || (u2 == v && o2 < l)) rank++;
        }
        sv[(size_t)mat * 32 + rank] = v;
    }
}

// ---------------- reg loss reduction ----------------
__global__ __launch_bounds__(128) void reg_k(const float* __restrict__ sv,
                                             float* __restrict__ out)
{
    __shared__ float red[128];
    int t = threadIdx.x;
    float val = 0.f;
    if (t < 96) {
        int p = t >> 5, d = t & 31;
        float s = 0;
        #pragma unroll
        for (int k = 0; k < 16; k++) s += sv[(size_t)(p * 16 + k) * 32 + d];
        s *= (1.f / 16.f);
        val = s * s;
    }
    red[t] = val; __syncthreads();
    for (int off = 64; off > 0; off >>= 1) {
        if (t < off) red[t] += red[t + off];
        __syncthreads();
    }
    if (t == 0) out[B_] = 0.01f * red[0] / 96.f;
}

extern "C" void kernel_launch(void* const* d_in, const int* in_sizes, int n_in,
                              void* d_out, int out_size, void* d_ws, size_t ws_size,
                              hipStream_t stream)
{
    const int*   x      = (const int*)d_in[0];
    const float* emb    = (const float*)d_in[1];
    const float* crossW = (const float*)d_in[2];
    const float* crossb = (const float*)d_in[3];
    const float* mlp1W  = (const float*)d_in[4];
    const float* mlp1b  = (const float*)d_in[5];
    const float* W1     = (const float*)d_in[6];
    const float* b1     = (const float*)d_in[7];
    const float* W2     = (const float*)d_in[8];
    const float* b2     = (const float*)d_in[9];
    const float* W3     = (const float*)d_in[10];
    const float* b3     = (const float*)d_in[11];
    float* out = (float*)d_out;

    unsigned char* wsb = (unsigned char*)d_ws;
    size_t o = 0;
    auto alloc = [&](size_t bytes) -> void* {
        void* p = wsb + o; o += (bytes + 255) & ~(size_t)255; return p;
    };
    unsigned short* esb  = (unsigned short*)alloc(3 * BE_ * 2);
    unsigned short* B0   = (unsigned short*)alloc(3 * BE_ * 2);
    unsigned short* B1   = (unsigned short*)alloc(3 * BE_ * 2);
    unsigned short* WtC  = (unsigned short*)alloc((size_t)9 * 512 * 512 * 2);
    unsigned short* WtM  = (unsigned short*)alloc((size_t)3 * 512 * 512 * 2);
    unsigned short* Wt1  = (unsigned short*)alloc((size_t)512 * 256 * 2);
    unsigned short* Wt2  = (unsigned short*)alloc((size_t)256 * 128 * 2);
    float*          mbuf = (float*)alloc(48 * 1024 * 4);
    float*          svb  = (float*)alloc(48 * 32 * 4);
    // hsb/h1b/h2b alias onto B0 (dead after mlp1 GEMM)
    unsigned short* hsb = B0;
    unsigned short* h1b = B0 + (size_t)B_ * M1_;
    unsigned short* h2b = h1b + (size_t)B_ * M2_;

    // weights -> bf16 transposed [N][K]
    wtrans_k<<<dim3(16, 16, 9), 256, 0, stream>>>(crossW, WtC, 512, 512);
    wtrans_k<<<dim3(16, 16, 3), 256, 0, stream>>>(mlp1W,  WtM, 512, 512);
    wtrans_k<<<dim3( 8, 16, 1), 256, 0, stream>>>(W1, Wt1, 512, 256);
    wtrans_k<<<dim3( 4,  8, 1), 256, 0, stream>>>(W2, Wt2, 256, 128);

    gather_k<<<(NE_ * B_ * F_ * 4) / 256, 256, 0, stream>>>(x, emb, esb);

    // regularization path
    hipMemsetAsync(mbuf, 0, 48 * 1024 * 4, stream);
    pairsum_k<<<dim3(48, 16), 256, 0, stream>>>(esb, mbuf);
    svd_k<<<12, 256, 0, stream>>>(mbuf, svb);
    reg_k<<<1, 128, 0, stream>>>(svb, out);

    // main path: 3 branches fused over blockIdx.z
    const long sW512 = 3 * 512 * 512;   // per-e stride in cross weights
    gemm_mfma_k<<<dim3(4, 64, 3), 256, 0, stream>>>(
        esb, (long)BE_, WtC, sW512, crossb, 3 * 512,
        esb, (long)BE_, esb, (long)BE_, B0, (long)BE_, B_, EOD_, EOD_, 0);
    gemm_mfma_k<<<dim3(4, 64, 3), 256, 0, stream>>>(
        B0, (long)BE_, WtC + 512 * 512, sW512, crossb + 512, 3 * 512,
        esb, (long)BE_, B0, (long)BE_, B1, (long)BE_, B_, EOD_, EOD_, 0);
    gemm_mfma_k<<<dim3(4, 64, 3), 256, 0, stream>>>(
        B1, (long)BE_, WtC + 2 * 512 * 512, sW512, crossb + 1024, 3 * 512,
        esb, (long)BE_, B1, (long)BE_, B0, (long)BE_, B_, EOD_, EOD_, 0);
    gemm_mfma_k<<<dim3(4, 64, 3), 256, 0, stream>>>(
        B0, (long)BE_, WtM, 512 * 512, mlp1b, 512,
        nullptr, 0, nullptr, 0, B1, (long)BE_, B_, M1_, EOD_, 1);
    sum3_k<<<(B_ * M1_) / (256 * 8), 256, 0, stream>>>(B1, hsb);
    gemm_mfma_k<<<dim3(2, 64, 1), 256, 0, stream>>>(
        hsb, 0, Wt1, 0, b1, 0, nullptr, 0, nullptr, 0,
        h1b, 0, B_, M2_, M1_, 2);
    gemm_mfma_k<<<dim3(1, 64, 1), 256, 0, stream>>>(
        h1b, 0, Wt2, 0, b2, 0, nullptr, 0, nullptr, 0,
        h2b, 0, B_, M3_, M2_, 2);
    final_k<<<(B_ * 64) / 256, 256, 0, stream>>>(h2b, W3, b3, out);
}

// Round 4
// 704.009 us; speedup vs baseline: 2.4353x; 1.1605x over previous
//
#include <hip/hip_runtime.h>
#include <math.h>

#define B_ 8192
#define F_ 16
#define V_ 50000
#define D_ 32
#define NE_ 3
#define EOD_ 512
#define M1_ 512
#define M2_ 256
#define M3_ 128
#define BE_ ((size_t)B_ * EOD_)

typedef __attribute__((ext_vector_type(8))) short short8;
typedef __attribute__((ext_vector_type(4))) float floatx4;

__device__ __forceinline__ unsigned short f2bf(float f) {
    union { float f; unsigned u; } v; v.f = f;
    unsigned r = v.u + 0x7FFF + ((v.u >> 16) & 1);
    return (unsigned short)(r >> 16);
}
__device__ __forceinline__ float bf2f(unsigned short h) {
    union { unsigned u; float f; } v; v.u = (unsigned)h << 16;
    return v.f;
}
// async global->LDS, 16B per lane; LDS dest must be wave-uniform base + lane*16
__device__ __forceinline__ void gld16(const void* g, void* l) {
    __builtin_amdgcn_global_load_lds(
        (const __attribute__((address_space(1))) unsigned int*)g,
        (__attribute__((address_space(3))) unsigned int*)l, 16, 0, 0);
}

// ---------------- embedding gather (fp32 tables -> bf16 es) ----------------
__global__ __launch_bounds__(256) void gather_k(const int* __restrict__ x,
    const float* __restrict__ tables, unsigned short* __restrict__ esb)
{
    int gid = blockIdx.x * 256 + threadIdx.x;   // NE*B*F*4 threads, 8 elems each
    int d8 = gid & 3;
    int f  = (gid >> 2) & 15;
    int b  = (gid >> 6) & (B_ - 1);
    int e  = gid >> 19;
    int idx = x[b * F_ + f] + f * V_;
    const float4* src = (const float4*)(tables + ((size_t)e * F_ * V_ + idx) * D_) + d8 * 2;
    float4 v0 = src[0], v1 = src[1];
    unsigned short o[8];
    o[0] = f2bf(v0.x); o[1] = f2bf(v0.y); o[2] = f2bf(v0.z); o[3] = f2bf(v0.w);
    o[4] = f2bf(v1.x); o[5] = f2bf(v1.y); o[6] = f2bf(v1.z); o[7] = f2bf(v1.w);
    unsigned short* dst = esb + ((size_t)e * B_ + b) * EOD_ + f * D_ + d8 * 8;
    *(uint4*)dst = *(uint4*)o;
}

// ------------- weight transpose+convert: fp32 W[K][N] -> bf16 Wt[N][K] -------------
// z<9: crossW matrices; z>=9: mlp1W matrices (all 512x512)
__global__ __launch_bounds__(256) void wtrans12_k(const float* __restrict__ crossW,
    const float* __restrict__ mlp1W, unsigned short* __restrict__ Wt)
{
    __shared__ float tile[32][33];
    int bn = blockIdx.x * 32, bk = blockIdx.y * 32;
    int mat = blockIdx.z;
    const float* Wm = (mat < 9) ? crossW + (size_t)mat * 512 * 512
                                : mlp1W + (size_t)(mat - 9) * 512 * 512;
    unsigned short* Wtm = Wt + (size_t)mat * 512 * 512;
    int tx = threadIdx.x & 31, ty = threadIdx.x >> 5;   // 32 x 8
    #pragma unroll
    for (int i = 0; i < 32; i += 8)
        tile[ty + i][tx] = Wm[(size_t)(bk + ty + i) * 512 + bn + tx];
    __syncthreads();
    #pragma unroll
    for (int i = 0; i < 32; i += 8)
        Wtm[(size_t)(bn + ty + i) * 512 + bk + tx] = f2bf(tile[tx][ty + i]);
}

__global__ __launch_bounds__(256) void wtrans_k(const float* __restrict__ W,
    unsigned short* __restrict__ Wt, int K, int N)
{
    __shared__ float tile[32][33];
    int bn = blockIdx.x * 32, bk = blockIdx.y * 32;
    int tx = threadIdx.x & 31, ty = threadIdx.x >> 5;
    #pragma unroll
    for (int i = 0; i < 32; i += 8)
        tile[ty + i][tx] = W[(size_t)(bk + ty + i) * N + bn + tx];
    __syncthreads();
    #pragma unroll
    for (int i = 0; i < 32; i += 8)
        Wt[(size_t)(bn + ty + i) * K + bk + tx] = f2bf(tile[tx][ty + i]);
}

// ---------------- bf16 MFMA GEMM, 128x128 tile, BK=32, z-batched ----------------
// out = epi(A[M][K] @ Wt[N][K]^T + bias); per-e strides via blockIdx.z
// mode 0: v = x0*v + xl ; mode 1: v = relu(v)/3 ; mode 2: v = relu(v)
__global__ __launch_bounds__(256) void gemm_mfma_k(
    const unsigned short* __restrict__ A,  long sA,
    const unsigned short* __restrict__ Wt, long sW,
    const float* __restrict__ bias,        long sB,
    const unsigned short* __restrict__ x0, long sX,
    const unsigned short* __restrict__ xl, long sXl,
    unsigned short* __restrict__ outb,     long sO,
    int M, int N, int K, int mode)
{
    int e = blockIdx.z;
    A    += (size_t)e * sA;
    Wt   += (size_t)e * sW;
    bias += (size_t)e * sB;
    outb += (size_t)e * sO;
    if (mode == 0) { x0 += (size_t)e * sX; xl += (size_t)e * sXl; }

    __shared__ unsigned short As[128 * 32];
    __shared__ unsigned short Bs[128 * 32];
    int t = threadIdx.x;
    int w = t >> 6, lane = t & 63;
    int quad = lane >> 4, lid = lane & 15;
    int wr = (w & 1) * 64, wc = (w >> 1) * 64;
    int rowbase = blockIdx.y * 128, colbase = blockIdx.x * 128;

    int chunk = w * 2;
    int sub = lane >> 2;
    int kk = (lane & 3) * 8;
    const unsigned short* pa0 = A  + (size_t)(rowbase + chunk * 16 + sub) * K + kk;
    const unsigned short* pa1 = pa0 + (size_t)16 * K;
    const unsigned short* pb0 = Wt + (size_t)(colbase + chunk * 16 + sub) * K + kk;
    const unsigned short* pb1 = pb0 + (size_t)16 * K;
    unsigned short* la0 = As + chunk * 512 + lane * 8;
    unsigned short* la1 = la0 + 512;
    unsigned short* lb0 = Bs + chunk * 512 + lane * 8;
    unsigned short* lb1 = lb0 + 512;

    floatx4 acc[4][4];
    #pragma unroll
    for (int i = 0; i < 4; i++)
        #pragma unroll
        for (int j = 0; j < 4; j++) acc[i][j] = {0.f, 0.f, 0.f, 0.f};

    for (int k0 = 0; k0 < K; k0 += 32) {
        if (k0) __syncthreads();
        gld16(pa0 + k0, la0);
        gld16(pa1 + k0, la1);
        gld16(pb0 + k0, lb0);
        gld16(pb1 + k0, lb1);
        __syncthreads();
        short8 af[4], bfr[4];
        #pragma unroll
        for (int i = 0; i < 4; i++) {
            af[i]  = *(const short8*)(As + (wr + i * 16 + lid) * 32 + quad * 8);
            bfr[i] = *(const short8*)(Bs + (wc + i * 16 + lid) * 32 + quad * 8);
        }
        #pragma unroll
        for (int i = 0; i < 4; i++)
            #pragma unroll
            for (int j = 0; j < 4; j++)
                acc[i][j] = __builtin_amdgcn_mfma_f32_16x16x32_bf16(af[i], bfr[j], acc[i][j], 0, 0, 0);
    }

    // C/D layout: col = lane&15, row = quad*4 + reg
    #pragma unroll
    for (int i = 0; i < 4; i++) {
        int row0 = rowbase + wr + i * 16 + quad * 4;
        #pragma unroll
        for (int j = 0; j < 4; j++) {
            int col = colbase + wc + j * 16 + lid;
            float bv = bias[col];
            #pragma unroll
            for (int rr = 0; rr < 4; rr++) {
                size_t off = (size_t)(row0 + rr) * N + col;
                float v = acc[i][j][rr] + bv;
                if (mode == 0)      v = bf2f(x0[off]) * v + bf2f(xl[off]);
                else if (mode == 1) v = fmaxf(v, 0.f) * (1.f / 3.f);
                else                v = fmaxf(v, 0.f);
                outb[off] = f2bf(v);
            }
        }
    }
}

// ---------------- sum of 3 per-e mlp1 outputs (bf16) ----------------
__global__ __launch_bounds__(256) void sum3_k(const unsigned short* __restrict__ h,
                                              unsigned short* __restrict__ o)
{
    size_t i = ((size_t)blockIdx.x * 256 + threadIdx.x) * 8;
    uint4 a = *(const uint4*)(h + i);
    uint4 b = *(const uint4*)(h + BE_ + i);
    uint4 c = *(const uint4*)(h + 2 * BE_ + i);
    const unsigned short* pa = (const unsigned short*)&a;
    const unsigned short* pb = (const unsigned short*)&b;
    const unsigned short* pc = (const unsigned short*)&c;
    unsigned short r[8];
    #pragma unroll
    for (int j = 0; j < 8; j++) r[j] = f2bf(bf2f(pa[j]) + bf2f(pb[j]) + bf2f(pc[j]));
    *(uint4*)(o + i) = *(uint4*)r;
}

// ---------------- final 128->1 dot + sigmoid (bf16 h2) ----------------
__global__ __launch_bounds__(256) void final_k(const unsigned short* __restrict__ h2,
    const float* __restrict__ W3, const float* __restrict__ b3,
    float* __restrict__ out)
{
    int gt = blockIdx.x * 256 + threadIdx.x;
    int s = gt >> 6, lane = gt & 63;
    float p = bf2f(h2[(size_t)s * 128 + lane]) * W3[lane]
            + bf2f(h2[(size_t)s * 128 + 64 + lane]) * W3[64 + lane];
    #pragma unroll
    for (int off = 32; off > 0; off >>= 1) p += __shfl_down(p, off);
    if (lane == 0) out[s] = 1.0f / (1.0f + expf(-(p + b3[0])));
}

// ---------------- pair Gram accumulation (bf16 in, fp32 accum) ----------------
__global__ __launch_bounds__(256) void pairsum_k(const unsigned short* __restrict__ es,
                                                 float* __restrict__ m)
{
    const int pi[3] = {1, 2, 2};
    const int pj[3] = {0, 0, 1};
    int pk = blockIdx.x;             // 0..47
    int pair = pk >> 4, k = pk & 15;
    const unsigned short* Ei = es + (size_t)pi[pair] * BE_ + k * D_;
    const unsigned short* Ej = es + (size_t)pj[pair] * BE_ + k * D_;
    int b0 = blockIdx.y * (B_ / 16);

    __shared__ float sa[8][32], sb[8][32];
    int t = threadIdx.x;
    int d = t >> 3, e4 = (t & 7) * 4;
    int lr = t >> 5, lc = t & 31;
    float a0 = 0, a1 = 0, a2 = 0, a3 = 0;

    for (int bb = b0; bb < b0 + B_ / 16; bb += 8) {
        __syncthreads();
        sa[lr][lc] = bf2f(Ei[(size_t)(bb + lr) * EOD_ + lc]);
        sb[lr][lc] = bf2f(Ej[(size_t)(bb + lr) * EOD_ + lc]);
        __syncthreads();
        #pragma unroll
        for (int s2 = 0; s2 < 8; s2++) {
            float avv = sa[s2][d];
            float4 bvv = *(const float4*)&sb[s2][e4];
            a0 += avv * bvv.x; a1 += avv * bvv.y;
            a2 += avv * bvv.z; a3 += avv * bvv.w;
        }
    }
    float* dst = m + (size_t)pk * 1024 + d * 32 + e4;
    atomicAdd(dst + 0, a0); atomicAdd(dst + 1, a1);
    atomicAdd(dst + 2, a2); atomicAdd(dst + 3, a3);
}

// ---------------- 32x32 singular values: one-sided Jacobi, register-resident ----------------
// One wave per matrix. Lane (half,col) holds 16 elements of column `col`
// (rows 16*half .. 16*half+15) in VGPRs. Per round: fetch partner column via
// shfl, 3 dots, cross-half reduce via shfl_xor(32), rotate. No LDS in loop.
__global__ __launch_bounds__(64) void svd_k(const float* __restrict__ mg,
                                            float* __restrict__ sv)
{
    int mat = blockIdx.x;
    int l = threadIdx.x;
    int col = l & 31, half = l >> 5;
    const float* src = mg + (size_t)mat * 1024 + half * 16 * 32 + col;
    float a[16];
    #pragma unroll
    for (int j = 0; j < 16; j++) a[j] = src[j * 32];

    for (int sweep = 0; sweep < 6; sweep++) {
        for (int r = 0; r < 31; r++) {
            // round-robin pairing: fixed player 31; (p,q)=((r+t)%31,(r-t)%31)
            int partner, isp;
            if (col == 31) { partner = r; isp = 1; }
            else {
                int u = col - r; if (u < 0) u += 31;
                if (u == 0) { partner = 31; isp = 0; }
                else {
                    int v = 2 * r - col; v %= 31; if (v < 0) v += 31;
                    partner = v;
                    isp = (u <= 15) ? 1 : 0;
                }
            }
            int plane = half * 32 + partner;
            float b[16];
            #pragma unroll
            for (int j = 0; j < 16; j++) b[j] = __shfl(a[j], plane, 64);
            float own = 0.f, cross = 0.f, par = 0.f;
            #pragma unroll
            for (int j = 0; j < 16; j++) {
                own   += a[j] * a[j];
                cross += a[j] * b[j];
                par   += b[j] * b[j];
            }
            own   += __shfl_xor(own, 32);
            cross += __shfl_xor(cross, 32);
            par   += __shfl_xor(par, 32);
            float app = isp ? own : par;
            float aqq = isp ? par : own;
            float c = 1.f, s = 0.f;
            if (fabsf(cross) > 1e-12f) {
                float tau = (aqq - app) / (2.f * cross);
                float tt = (tau >= 0.f) ? 1.f / (tau + sqrtf(1.f + tau * tau))
                                        : 1.f / (tau - sqrtf(1.f + tau * tau));
                c = rsqrtf(1.f + tt * tt); s = tt * c;
            }
            float sgn = isp ? -s : s;
            #pragma unroll
            for (int j = 0; j < 16; j++) a[j] = c * a[j] + sgn * b[j];
        }
    }

    // singular values = column norms
    float nn = 0.f;
    #pragma unroll
    for (int j = 0; j < 16; j++) nn += a[j] * a[j];
    nn += __shfl_xor(nn, 32);
    float v = sqrtf(nn);

    __shared__ float ev[32];
    if (half == 0) ev[col] = v;
    // single wave: LDS ops complete in program order, no barrier needed
    if (half == 0) {
        int rank = 0;
        for (int o2 = 0; o2 < 32; o2++) {
            float w = ev[o2];
            if (w > v || (w == v && o2 < col)) rank++;
        }
        sv[(size_t)mat * 32 + rank] = v;
    }
}

// ---------------- reg loss reduction ----------------
__global__ __launch_bounds__(128) void reg_k(const float* __restrict__ sv,
                                             float* __restrict__ out)
{
    __shared__ float red[128];
    int t = threadIdx.x;
    float val = 0.f;
    if (t < 96) {
        int p = t >> 5, d = t & 31;
        float s = 0;
        #pragma unroll
        for (int k = 0; k < 16; k++) s += sv[(size_t)(p * 16 + k) * 32 + d];
        s *= (1.f / 16.f);
        val = s * s;
    }
    red[t] = val; __syncthreads();
    for (int off = 64; off > 0; off >>= 1) {
        if (t < off) red[t] += red[t + off];
        __syncthreads();
    }
    if (t == 0) out[B_] = 0.01f * red[0] / 96.f;
}

extern "C" void kernel_launch(void* const* d_in, const int* in_sizes, int n_in,
                              void* d_out, int out_size, void* d_ws, size_t ws_size,
                              hipStream_t stream)
{
    const int*   x      = (const int*)d_in[0];
    const float* emb    = (const float*)d_in[1];
    const float* crossW = (const float*)d_in[2];
    const float* crossb = (const float*)d_in[3];
    const float* mlp1W  = (const float*)d_in[4];
    const float* mlp1b  = (const float*)d_in[5];
    const float* W1     = (const float*)d_in[6];
    const float* b1     = (const float*)d_in[7];
    const float* W2     = (const float*)d_in[8];
    const float* b2     = (const float*)d_in[9];
    const float* W3     = (const float*)d_in[10];
    const float* b3     = (const float*)d_in[11];
    float* out = (float*)d_out;

    unsigned char* wsb = (unsigned char*)d_ws;
    size_t o = 0;
    auto alloc = [&](size_t bytes) -> void* {
        void* p = wsb + o; o += (bytes + 255) & ~(size_t)255; return p;
    };
    unsigned short* esb  = (unsigned short*)alloc(3 * BE_ * 2);
    unsigned short* B0   = (unsigned short*)alloc(3 * BE_ * 2);
    unsigned short* B1   = (unsigned short*)alloc(3 * BE_ * 2);
    unsigned short* WtC  = (unsigned short*)alloc((size_t)12 * 512 * 512 * 2);
    unsigned short* Wt1  = (unsigned short*)alloc((size_t)512 * 256 * 2);
    unsigned short* Wt2  = (unsigned short*)alloc((size_t)256 * 128 * 2);
    float*          mbuf = (float*)alloc(48 * 1024 * 4);
    float*          svb  = (float*)alloc(48 * 32 * 4);
    unsigned short* WtM  = WtC + (size_t)9 * 512 * 512;
    // hsb/h1b/h2b alias onto B0 (dead after mlp1 GEMM)
    unsigned short* hsb = B0;
    unsigned short* h1b = B0 + (size_t)B_ * M1_;
    unsigned short* h2b = h1b + (size_t)B_ * M2_;

    // weights -> bf16 transposed [N][K]
    wtrans12_k<<<dim3(16, 16, 12), 256, 0, stream>>>(crossW, mlp1W, WtC);
    wtrans_k<<<dim3( 8, 16), 256, 0, stream>>>(W1, Wt1, 512, 256);
    wtrans_k<<<dim3( 4,  8), 256, 0, stream>>>(W2, Wt2, 256, 128);

    gather_k<<<(NE_ * B_ * F_ * 4) / 256, 256, 0, stream>>>(x, emb, esb);

    // regularization path
    hipMemsetAsync(mbuf, 0, 48 * 1024 * 4, stream);
    pairsum_k<<<dim3(48, 16), 256, 0, stream>>>(esb, mbuf);
    svd_k<<<48, 64, 0, stream>>>(mbuf, svb);
    reg_k<<<1, 128, 0, stream>>>(svb, out);

    // main path: 3 branches fused over blockIdx.z
    const long sW512 = 3 * 512 * 512;   // per-e stride in cross weights
    gemm_mfma_k<<<dim3(4, 64, 3), 256, 0, stream>>>(
        esb, (long)BE_, WtC, sW512, crossb, 3 * 512,
        esb, (long)BE_, esb, (long)BE_, B0, (long)BE_, B_, EOD_, EOD_, 0);
    gemm_mfma_k<<<dim3(4, 64, 3), 256, 0, stream>>>(
        B0, (long)BE_, WtC + 512 * 512, sW512, crossb + 512, 3 * 512,
        esb, (long)BE_, B0, (long)BE_, B1, (long)BE_, B_, EOD_, EOD_, 0);
    gemm_mfma_k<<<dim3(4, 64, 3), 256, 0, stream>>>(
        B1, (long)BE_, WtC + 2 * 512 * 512, sW512, crossb + 1024, 3 * 512,
        esb, (long)BE_, B1, (long)BE_, B0, (long)BE_, B_, EOD_, EOD_, 0);
    gemm_mfma_k<<<dim3(4, 64, 3), 256, 0, stream>>>(
        B0, (long)BE_, WtM, 512 * 512, mlp1b, 512,
        nullptr, 0, nullptr, 0, B1, (long)BE_, B_, M1_, EOD_, 1);
    sum3_k<<<(B_ * M1_) / (256 * 8), 256, 0, stream>>>(B1, hsb);
    gemm_mfma_k<<<dim3(2, 64, 1), 256, 0, stream>>>(
        hsb, 0, Wt1, 0, b1, 0, nullptr, 0, nullptr, 0,
        h1b, 0, B_, M2_, M1_, 2);
    gemm_mfma_k<<<dim3(1, 64, 1), 256, 0, stream>>>(
        h1b, 0, Wt2, 0, b2, 0, nullptr, 0, nullptr, 0,
        h2b, 0, B_, M3_, M2_, 2);
    final_k<<<(B_ * 64) / 256, 256, 0, stream>>>(h2b, W3, b3, out);
}